// Round 6
// baseline (132.744 us; speedup 1.0000x reference)
//
#include <hip/hip_runtime.h>
#include <hip/hip_bf16.h>

typedef __attribute__((ext_vector_type(8))) short bf16x8;
typedef __attribute__((ext_vector_type(4))) float f32x4;
typedef __attribute__((ext_vector_type(16))) float f32x16;

#define BATCH 32
#define SEQ   2048
#define PSTR  20    // fallback kernel only
#define KSTR  72    // fallback kernel only
#define VSTR  36    // fallback + prepkv staging
#define LOG2E 1.44269504088896340736f
#define QSCALE (0.125f * LOG2E)
#define NEGL  (-1000000.0f * LOG2E)

__device__ __forceinline__ unsigned int pk2(float lo, float hi) {
    __hip_bfloat162 h2 = __float22bfloat162_rn(make_float2(lo, hi));  // v_cvt_pk_bf16_f32
    return *reinterpret_cast<unsigned int*>(&h2);
}

__device__ __forceinline__ void dma16(const short* g, short* l) {
    __builtin_amdgcn_global_load_lds((const __attribute__((address_space(1))) void*)g,
                                     (__attribute__((address_space(3))) void*)l, 16, 0, 0);
}

// v_permlane32_swap_b32: a[32:63] <-> b[0:31].
__device__ __forceinline__ void plswap(unsigned int& a, unsigned int& b) {
    asm volatile("v_permlane32_swap_b32 %0, %1" : "+v"(a), "+v"(b));
}

// standalone prep (fallback path only)
__global__ void prep_vl(const int* __restrict__ VL, int* __restrict__ meta) {
    __shared__ int sv[BATCH];
    const int t = threadIdx.x;
    int odd = (t < 16) ? VL[2 * t + 1] : 0;
    const bool is64 = (__ballot(odd != 0) == 0ULL);
    if (t < BATCH) {
        int x = is64 ? VL[2 * t] : VL[t];
        x = x < 0 ? 0 : (x > SEQ ? SEQ : x);
        sv[t] = x;
    }
    __syncthreads();
    if (t < BATCH) {
        const int x = sv[t];
        int rank = 0;
        for (int j = 0; j < BATCH; ++j) {
            const int y = sv[j];
            rank += (y > x) || (y == x && j < t);
        }
        meta[rank] = x;
        meta[BATCH + rank] = t;
    }
}

// K fp32->bf16 row-major [b][key][d]; V fp32->bf16 TILE-MAJOR transposed
// Vt[b][kt][d][64 keys] (packed key-pairs). Tiles beyond ceil128(vl[b]) are
// SKIPPED (round-6: attn stages 128-key chunks, so keep the chunk's second
// sub-tile initialized -> no garbage into PV). Block BATCH*32 does the meta
// rank-sort wave-synchronously.
__global__ __launch_bounds__(256) void prepkv(const float* __restrict__ Kp,
                                              const float* __restrict__ Vp,
                                              const int* __restrict__ VL,
                                              short* __restrict__ Kb,
                                              short* __restrict__ Vt,
                                              int* __restrict__ meta) {
    __shared__ unsigned int l[64 * VSTR];
    __shared__ int sv[BATCH];
    __shared__ int svl;
    const int tid = threadIdx.x;
    if (blockIdx.x == BATCH * 32) {
        if (tid < 64) {
            int odd = (tid < 16) ? VL[2 * tid + 1] : 0;
            const bool is64 = (__ballot(odd != 0) == 0ULL);   // lens>=1
            if (tid < BATCH) {
                int x = is64 ? VL[2 * tid] : VL[tid];
                x = x < 0 ? 0 : (x > SEQ ? SEQ : x);
                sv[tid] = x;
            }
            asm volatile("s_waitcnt lgkmcnt(0)" ::: "memory");
            if (tid < BATCH) {
                const int x = sv[tid];
                int rank = 0;
                for (int j = 0; j < BATCH; ++j) {
                    const int y = sv[j];
                    rank += (y > x) || (y == x && j < tid);
                }
                meta[rank] = x;
                meta[BATCH + rank] = tid;
            }
        }
        return;
    }
    const int b = blockIdx.x >> 5, kt = blockIdx.x & 31, kb = kt * 64;
    // per-block vl: skip tiles attn never stages (128-chunk granularity)
    if (tid < 64) {
        int odd = (tid < 16) ? VL[2 * tid + 1] : 0;
        const bool is64 = (__ballot(odd != 0) == 0ULL);
        if (tid == 0) {
            int x = is64 ? VL[2 * b] : VL[b];
            x = x < 0 ? 0 : (x > SEQ ? SEQ : x);
            svl = x;
        }
    }
    __syncthreads();
    if (kb >= ((svl + 127) & ~127)) return;   // block-uniform exit
    const float* Kv = Kp + ((size_t)b * SEQ + kb) * 64;
    const float* Vb = Vp + ((size_t)b * SEQ + kb) * 64;
    #pragma unroll
    for (int h = 0; h < 4; ++h) {
        const int c = tid + h * 256;
        const int row = c >> 4, col = (c & 15) * 4;
        f32x4 x = *(const f32x4*)(Kv + row * 64 + col);
        unsigned int* dst = (unsigned int*)(Kb + ((size_t)b * SEQ + kb + row) * 64 + col);
        dst[0] = pk2(x[0], x[1]); dst[1] = pk2(x[2], x[3]);
    }
    #pragma unroll
    for (int h = 0; h < 2; ++h) {
        const int u = tid + h * 256;
        const int d4 = (u & 3) + ((u >> 7) << 2);
        const int kp = (u >> 2) & 31;
        f32x4 a = *(const f32x4*)(Vb + (2 * kp) * 64 + d4 * 4);
        f32x4 c = *(const f32x4*)(Vb + (2 * kp + 1) * 64 + d4 * 4);
        #pragma unroll
        for (int j = 0; j < 4; ++j)
            l[(d4 * 4 + j) * VSTR + kp] = pk2(a[j], c[j]);
    }
    __syncthreads();
    // tile-major write: uint index ((b*32+kt)*64 + d)*32 + kp -> contiguous 8 KB/block
    const int d = tid >> 2, cg = tid & 3;
    unsigned int w[8];
    #pragma unroll
    for (int j = 0; j < 8; ++j) w[j] = l[d * VSTR + cg * 8 + j];
    unsigned int* dst = (unsigned int*)Vt + ((size_t)(b * 32 + kt) * 64 + d) * 32 + cg * 8;
    #pragma unroll
    for (int j = 0; j < 8; ++j) dst[j] = w[j];
}

// ---- main: round-6 restructure for BACKFILL (r5 post-mortem: 3 schedules all
// ~45-50us; occupancy 30% vs 50% ceiling -> tail-bound, not ILP-bound).
// 512-thread blocks (8 waves = 2 qh x 4 kh) process 128-key chunks: per-wave
// per-barrier work identical to r5, but half the barriers and half the item
// critical path. Grid 1024 items, only 512 resident (2 blk/CU, 64KB LDS) ->
// hardware queue backfills; LPT order (rank 0 = longest first) -> tail ~0.
// Math core (32x32 MFMA, log2-domain no-max softmax, in-reg P^T) unchanged. ----
__global__ __launch_bounds__(512, 4)
void attn_fwd(const float* __restrict__ Qp, const short* __restrict__ Kb,
              const short* __restrict__ Vt, const int* __restrict__ meta,
              float* __restrict__ Out) {
    constexpr int S = SEQ;
    __shared__ short bK2[2 * 8192];   // [buf][128 rows][64 bf16] = 32 KB
    __shared__ short bV2[2 * 8192];   // [buf][2 sub-tiles][64 d][64 keys] = 32 KB

    const int tid  = threadIdx.x;
    const int wave = tid >> 6, lane = tid & 63;
    const int r31 = lane & 31, hi = lane >> 5;
    const int l7  = lane & 7;
    const int qh = wave >> 2, kh = wave & 3;   // q-half, key-quarter (of 128)

    // LPT: rank-major blockIdx -> largest slots dispatched first, small backfill
    const int slot = blockIdx.x >> 5;
    const int qt   = blockIdx.x & 31;

    const int vl = meta[slot], batch = meta[BATCH + slot];
    const int nchunks = (vl + 127) >> 7;

    const short* Kbb = Kb + (size_t)batch * S * 64;
    const short* Vtb = Vt + (size_t)batch * 32 * 4096;   // tile-major: 4096 shorts/tile

    // staging: 8 waves x 16 rows = 128 rows/chunk; source-side XOR swizzle
    // (linear LDS dest + pre-swizzled global source + swizzled read):
    // LDS[row][slot s] = G[row][s ^ (row&7)].
    const int r8 = lane >> 3, s8 = lane & 7, csw = s8 ^ r8;
    const short* gK0 = Kbb + (wave * 16 + r8) * 64 + csw * 8;
    const short* gV0 = Vtb + (wave * 16 + r8) * 64 + csw * 8;
    short* lK0 = &bK2[wave * 16 * 64];
    short* lV0 = &bV2[wave * 16 * 64];

    // Q B-fragments: lane holds Q[qh*32+r31][kf*16+hi*8+j], scale folded
    // (scores exit MFMA in log2 domain)
    bf16x8 qf[4];
    {
        const float* qb = Qp + ((size_t)batch * S + qt * 64 + qh * 32 + r31) * 64 + hi * 8;
        #pragma unroll
        for (int kf = 0; kf < 4; ++kf) {
            f32x4 a = *(const f32x4*)(qb + kf * 16);
            f32x4 c = *(const f32x4*)(qb + kf * 16 + 4);
            union { bf16x8 v; unsigned int u[4]; } qq;
            qq.u[0] = pk2(a[0] * QSCALE, a[1] * QSCALE);
            qq.u[1] = pk2(a[2] * QSCALE, a[3] * QSCALE);
            qq.u[2] = pk2(c[0] * QSCALE, c[1] * QSCALE);
            qq.u[3] = pk2(c[2] * QSCALE, c[3] * QSCALE);
            qf[kf] = qq.v;
        }
    }

    f32x16 o0, o1, zv;
    #pragma unroll
    for (int r = 0; r < 16; ++r) { o0[r] = 0.f; o1[r] = 0.f; zv[r] = 0.f; }
    float lpart = 0.f;                      // per-lane partial Σp; merged ONCE at end
    const int krow = kh * 32 + r31;         // 0..127 within chunk
    const int vrow0 = (kh >> 1) * 64 + r31; // V LDS row (sub-tile select + d)
    const int vc0 = (kh & 1) * 4 + hi;      // V chunk column index

    if (nchunks > 0) {
        dma16(gK0,       lK0);
        dma16(gK0 + 512, lK0 + 512);
        dma16(gV0,       lV0);
        dma16(gV0 + 512, lV0 + 512);
    }

    for (int kt = 0; kt < nchunks; ++kt) {
        __syncthreads();   // publishes chunk kt (drains own DMA); frees other buf
        if (kt + 1 < nchunks) {
            const int ko = (kt + 1) * 8192;           // shorts per 128-key chunk
            short* ktgt = lK0 + (((kt + 1) & 1) << 13);
            short* vtgt = lV0 + (((kt + 1) & 1) << 13);
            dma16(gK0 + ko,       ktgt);
            dma16(gK0 + ko + 512, ktgt + 512);
            dma16(gV0 + ko,       vtgt);
            dma16(gV0 + ko + 512, vtgt + 512);
        }

        if (kt * 128 + kh * 32 < vl) {   // wave-uniform guard
            const char* cK = (const char*)bK2 + ((kt & 1) << 14);
            const char* cV = (const char*)bV2 + ((kt & 1) << 14);
            f32x16 st;
            __builtin_amdgcn_s_setprio(1);
            {   // QK: 32 keys (kh quarter) x 32 q (qh half), log2 domain
                bf16x8 k0 = *(const bf16x8*)(cK + krow * 128 + (((0 + hi) ^ l7) << 4));
                bf16x8 k1 = *(const bf16x8*)(cK + krow * 128 + (((2 + hi) ^ l7) << 4));
                bf16x8 k2 = *(const bf16x8*)(cK + krow * 128 + (((4 + hi) ^ l7) << 4));
                bf16x8 k3 = *(const bf16x8*)(cK + krow * 128 + (((6 + hi) ^ l7) << 4));
                st = __builtin_amdgcn_mfma_f32_32x32x16_bf16(k0, qf[0], zv, 0, 0, 0);
                st = __builtin_amdgcn_mfma_f32_32x32x16_bf16(k1, qf[1], st, 0, 0, 0);
                st = __builtin_amdgcn_mfma_f32_32x32x16_bf16(k2, qf[2], st, 0, 0, 0);
                st = __builtin_amdgcn_mfma_f32_32x32x16_bf16(k3, qf[3], st, 0, 0, 0);
            }
            __builtin_amdgcn_s_setprio(0);

            // mask the last partial 32-key quarter (wave-uniform branch)
            const int rem = vl - (kt * 128 + kh * 32);
            if (rem < 32) {
                #pragma unroll
                for (int r = 0; r < 16; ++r) {
                    const int kl = 4 * hi + (r & 3) + 8 * (r >> 2);
                    st[r] = (kl < rem) ? st[r] : NEGL;
                }
            }

            // p = exp2(s') (no max subtraction; masked -> exactly 0)
            #pragma unroll
            for (int r = 0; r < 16; ++r) st[r] = exp2f(st[r]);
            {
                const float a0 = (st[0] + st[1]) + (st[2] + st[3]);
                const float a1 = (st[4] + st[5]) + (st[6] + st[7]);
                const float a2 = (st[8] + st[9]) + (st[10] + st[11]);
                const float a3 = (st[12] + st[13]) + (st[14] + st[15]);
                lpart += (a0 + a1) + (a2 + a3);
            }

            // in-register P^T -> PV B-fragments (T12)
            union { bf16x8 v; unsigned int u[4]; } pf0, pf1;
            {
                unsigned int x0 = pk2(st[0], st[1]),   y0 = pk2(st[4], st[5]);
                unsigned int x1 = pk2(st[2], st[3]),   y1 = pk2(st[6], st[7]);
                plswap(x0, y0); plswap(x1, y1);
                pf0.u[0] = x0; pf0.u[1] = x1; pf0.u[2] = y0; pf0.u[3] = y1;
                unsigned int x2 = pk2(st[8], st[9]),   y2 = pk2(st[12], st[13]);
                unsigned int x3 = pk2(st[10], st[11]), y3 = pk2(st[14], st[15]);
                plswap(x2, y2); plswap(x3, y3);
                pf1.u[0] = x2; pf1.u[1] = x3; pf1.u[2] = y2; pf1.u[3] = y3;
            }

            // O^T += V^T P^T over this wave's 32 keys
            __builtin_amdgcn_s_setprio(1);
            {
                bf16x8 vf0 = *(const bf16x8*)(cV + vrow0 * 128 + ((vc0 ^ l7) << 4));
                o0 = __builtin_amdgcn_mfma_f32_32x32x16_bf16(vf0, pf0.v, o0, 0, 0, 0);
                bf16x8 vf1 = *(const bf16x8*)(cV + vrow0 * 128 + (((vc0 + 2) ^ l7) << 4));
                o0 = __builtin_amdgcn_mfma_f32_32x32x16_bf16(vf1, pf1.v, o0, 0, 0, 0);
                bf16x8 vf2 = *(const bf16x8*)(cV + (vrow0 + 32) * 128 + ((vc0 ^ l7) << 4));
                o1 = __builtin_amdgcn_mfma_f32_32x32x16_bf16(vf2, pf0.v, o1, 0, 0, 0);
                bf16x8 vf3 = *(const bf16x8*)(cV + (vrow0 + 32) * 128 + (((vc0 + 2) ^ l7) << 4));
                o1 = __builtin_amdgcn_mfma_f32_32x32x16_bf16(vf3, pf1.v, o1, 0, 0, 0);
            }
            __builtin_amdgcn_s_setprio(0);
        }
    }

    // per-(q, key-quarter) l: lanes l and l+32 hold complementary row sets
    float lw = lpart + __shfl_xor(lpart, 32);

    // cross-wave merge tree (kh0+=kh1, kh2+=kh3, then kh0+=kh2)
    __syncthreads();                          // all waves done reading K/V buffers
    float* mA = (float*)bK2;                  // 16 KB: [qh][32 regs][64 lanes]
    float* mB = (float*)bV2;
    float* lA = (float*)bK2 + 4096;
    float* lB = (float*)bV2 + 4096;
    if (kh == 1 || kh == 3) {
        float* m = (kh == 1) ? mA : mB;
        float* lv = (kh == 1) ? lA : lB;
        #pragma unroll
        for (int r = 0; r < 16; ++r) m[qh * 2048 + r * 64 + lane] = o0[r];
        #pragma unroll
        for (int r = 0; r < 16; ++r) m[qh * 2048 + (16 + r) * 64 + lane] = o1[r];
        lv[qh * 64 + lane] = lw;
    }
    __syncthreads();
    if (kh == 0 || kh == 2) {
        const float* m = (kh == 0) ? mA : mB;
        const float* lv = (kh == 0) ? lA : lB;
        #pragma unroll
        for (int r = 0; r < 16; ++r) o0[r] += m[qh * 2048 + r * 64 + lane];
        #pragma unroll
        for (int r = 0; r < 16; ++r) o1[r] += m[qh * 2048 + (16 + r) * 64 + lane];
        lw += lv[qh * 64 + lane];
    }
    __syncthreads();
    if (kh == 2) {
        #pragma unroll
        for (int r = 0; r < 16; ++r) mA[qh * 2048 + r * 64 + lane] = o0[r];
        #pragma unroll
        for (int r = 0; r < 16; ++r) mA[qh * 2048 + (16 + r) * 64 + lane] = o1[r];
        lA[qh * 64 + lane] = lw;
    }
    __syncthreads();
    if (kh == 0) {
        #pragma unroll
        for (int r = 0; r < 16; ++r) o0[r] += mA[qh * 2048 + r * 64 + lane];
        #pragma unroll
        for (int r = 0; r < 16; ++r) o1[r] += mA[qh * 2048 + (16 + r) * 64 + lane];
        lw += lA[qh * 64 + lane];
        const float inv = (lw > 0.f) ? 1.0f / lw : 0.f;
        const size_t orow = ((size_t)batch * S + qt * 64 + qh * 32 + r31) * 64;
        #pragma unroll
        for (int g4 = 0; g4 < 4; ++g4) {
            f32x4 w;
            #pragma unroll
            for (int j = 0; j < 4; ++j) w[j] = o0[g4 * 4 + j] * inv;
            *(f32x4*)(Out + orow + g4 * 8 + hi * 4) = w;
        }
        #pragma unroll
        for (int g4 = 0; g4 < 4; ++g4) {
            f32x4 w;
            #pragma unroll
            for (int j = 0; j < 4; ++j) w[j] = o1[g4 * 4 + j] * inv;
            *(f32x4*)(Out + orow + 32 + g4 * 8 + hi * 4) = w;
        }
    }
}

// ---------------- fallback (used only if ws too small) ----------------
__device__ __forceinline__ void load_tile_fb(const float* __restrict__ Kb,
                                             const float* __restrict__ Vb,
                                             int tid, f32x4 kv[4], f32x4 vv[4]) {
    #pragma unroll
    for (int h = 0; h < 4; ++h) {
        const int c = tid + h * 256;
        kv[h] = *(const f32x4*)(Kb + (c >> 4) * 64 + (c & 15) * 4);
    }
    #pragma unroll
    for (int h = 0; h < 2; ++h) {
        const int u  = tid + h * 256;
        const int d4 = (u & 3) + ((u >> 7) << 2);
        const int kp = (u >> 2) & 31;
        vv[2 * h]     = *(const f32x4*)(Vb + (2 * kp) * 64 + d4 * 4);
        vv[2 * h + 1] = *(const f32x4*)(Vb + (2 * kp + 1) * 64 + d4 * 4);
    }
}

__global__ __launch_bounds__(256, 4)
void attn_fb(const float* __restrict__ Qp, const float* __restrict__ Kp,
             const float* __restrict__ Vp, const int* __restrict__ meta,
             float* __restrict__ Out) {
    constexpr int S = SEQ;
    constexpr int qtiles = S >> 6;
    __shared__ short        lK [64 * KSTR];
    __shared__ unsigned int lVt[64 * VSTR];
    __shared__ unsigned int lPt[4 * 32 * PSTR];
    const int tid = threadIdx.x;
    const int wave = tid >> 6, lane = tid & 63;
    const int l15 = lane & 15, grp = lane >> 4;
    const int slot = blockIdx.x / qtiles, qt = blockIdx.x % qtiles;
    const int vl = meta[slot], batch = meta[BATCH + slot];
    const int ntiles = (vl + 63) >> 6;
    const float* Kb = Kp + (size_t)batch * S * 64;
    const float* Vb = Vp + (size_t)batch * S * 64;
    bf16x8 qf[2];
    {
        const float* qb = Qp + ((size_t)batch * S + qt * 64 + wave * 16 + l15) * 64 + grp * 8;
        #pragma unroll
        for (int kf = 0; kf < 2; ++kf) {
            f32x4 a = *(const f32x4*)(qb + kf * 32);
            f32x4 b = *(const f32x4*)(qb + kf * 32 + 4);
            union { bf16x8 v; unsigned int u[4]; } qq;
            qq.u[0] = pk2(a[0], a[1]); qq.u[1] = pk2(a[2], a[3]);
            qq.u[2] = pk2(b[0], b[1]); qq.u[3] = pk2(b[2], b[3]);
            qf[kf] = qq.v;
        }
    }
    f32x4 o[4] = {{0.f,0.f,0.f,0.f},{0.f,0.f,0.f,0.f},{0.f,0.f,0.f,0.f},{0.f,0.f,0.f,0.f}};
    float mrun = -INFINITY, lrun = 0.f;
    unsigned int* pw = &lPt[wave * 32 * PSTR];
    f32x4 kv[4], vv[4];
    if (ntiles > 0) load_tile_fb(Kb, Vb, tid, kv, vv);
    for (int kt = 0; kt < ntiles; ++kt) {
        const int kb = kt * 64;
        __syncthreads();
        #pragma unroll
        for (int h = 0; h < 4; ++h) {
            const int c = tid + h * 256;
            const int row = c >> 4, col = (c & 15) * 4;
            union { f32x4 f; float e[4]; } x; x.f = kv[h];
            unsigned int* dst = (unsigned int*)&lK[row * KSTR + col];
            dst[0] = pk2(x.e[0], x.e[1]); dst[1] = pk2(x.e[2], x.e[3]);
        }
        #pragma unroll
        for (int h = 0; h < 2; ++h) {
            const int u  = tid + h * 256;
            const int d4 = (u & 3) + ((u >> 7) << 2);
            const int kp = (u >> 2) & 31;
            union { f32x4 f; float e[4]; } a, b;
            a.f = vv[2 * h]; b.f = vv[2 * h + 1];
            #pragma unroll
            for (int j = 0; j < 4; ++j)
                lVt[(d4 * 4 + j) * VSTR + kp] = pk2(a.e[j], b.e[j]);
        }
        if (kt + 1 < ntiles) load_tile_fb(Kb + (size_t)(kb + 64) * 64, Vb + (size_t)(kb + 64) * 64, tid, kv, vv);
        __syncthreads();
        f32x4 st[4] = {{0.f,0.f,0.f,0.f},{0.f,0.f,0.f,0.f},{0.f,0.f,0.f,0.f},{0.f,0.f,0.f,0.f}};
        #pragma unroll
        for (int kf = 0; kf < 2; ++kf) {
            #pragma unroll
            for (int ct = 0; ct < 4; ++ct) {
                bf16x8 kfr = *(const bf16x8*)&lK[(ct * 16 + l15) * KSTR + kf * 32 + grp * 8];
                st[ct] = __builtin_amdgcn_mfma_f32_16x16x32_bf16(kfr, qf[kf], st[ct], 0, 0, 0);
            }
        }
        #pragma unroll
        for (int ct = 0; ct < 4; ++ct)
            #pragma unroll
            for (int r = 0; r < 4; ++r) {
                const bool valid = (kb + ct * 16 + grp * 4 + r) < vl;
                st[ct][r] = valid ? st[ct][r] * (0.125f * LOG2E) : NEGL;
            }
        float t0 = fmaxf(fmaxf(st[0][0], st[0][1]), fmaxf(st[0][2], st[0][3]));
        float t1 = fmaxf(fmaxf(st[1][0], st[1][1]), fmaxf(st[1][2], st[1][3]));
        float t2 = fmaxf(fmaxf(st[2][0], st[2][1]), fmaxf(st[2][2], st[2][3]));
        float t3 = fmaxf(fmaxf(st[3][0], st[3][1]), fmaxf(st[3][2], st[3][3]));
        float tm = fmaxf(fmaxf(t0, t1), fmaxf(t2, t3));
        tm = fmaxf(tm, __shfl_xor(tm, 16));
        tm = fmaxf(tm, __shfl_xor(tm, 32));
        const float mnew  = fmaxf(mrun, tm);
        const float alpha = exp2f(mrun - mnew);
        mrun = mnew;
        lrun *= alpha;
        #pragma unroll
        for (int dt = 0; dt < 4; ++dt)
            #pragma unroll
            for (int r = 0; r < 4; ++r) o[dt][r] *= alpha;
        float rs = 0.f;
        #pragma unroll
        for (int ct = 0; ct < 4; ++ct) {
            #pragma unroll
            for (int r = 0; r < 4; ++r) {
                st[ct][r] = exp2f(st[ct][r] - mrun);
                rs += st[ct][r];
            }
            #pragma unroll
            for (int a = 0; a < 2; ++a)
                pw[(ct * 8 + grp * 2 + a) * PSTR + l15] = pk2(st[ct][2 * a], st[ct][2 * a + 1]);
        }
        rs += __shfl_xor(rs, 16);
        rs += __shfl_xor(rs, 32);
        lrun += rs;
        asm volatile("s_waitcnt lgkmcnt(0)" ::: "memory");
        #pragma unroll
        for (int kk = 0; kk < 2; ++kk) {
            union { bf16x8 v; unsigned int u[4]; } pf;
            #pragma unroll
            for (int jj = 0; jj < 4; ++jj)
                pf.u[jj] = pw[(kk * 16 + grp * 4 + jj) * PSTR + l15];
            #pragma unroll
            for (int dt = 0; dt < 4; ++dt) {
                bf16x8 vf = *(const bf16x8*)&lVt[(dt * 16 + l15) * VSTR + kk * 16 + grp * 4];
                o[dt] = __builtin_amdgcn_mfma_f32_16x16x32_bf16(vf, pf.v, o[dt], 0, 0, 0);
            }
        }
    }
    const float inv = (lrun > 0.f) ? 1.0f / lrun : 0.f;
    const size_t orow = ((size_t)batch * S + qt * 64 + wave * 16 + l15) * 64;
    #pragma unroll
    for (int dt = 0; dt < 4; ++dt) {
        f32x4 w = o[dt];
        w[0] *= inv; w[1] *= inv; w[2] *= inv; w[3] *= inv;
        *(f32x4*)(Out + orow + dt * 16 + grp * 4) = w;
    }
}

extern "C" void kernel_launch(void* const* d_in, const int* in_sizes, int n_in,
                              void* d_out, int out_size, void* d_ws, size_t ws_size,
                              hipStream_t stream) {
    const float* Q  = (const float*)d_in[0];
    const float* K  = (const float*)d_in[1];
    const float* V  = (const float*)d_in[2];
    const int*   VL = (const int*)d_in[3];
    int* meta = (int*)d_ws;                    // 64 ints
    const size_t need = 512 + 2 * (size_t)BATCH * SEQ * 64 * sizeof(short);  // ~16.8 MB
    if (ws_size >= need) {
        short* Kb = (short*)((char*)d_ws + 512);
        short* Vt = Kb + (size_t)BATCH * SEQ * 64;
        prepkv<<<dim3(BATCH * 32 + 1), dim3(256), 0, stream>>>(K, V, VL, Kb, Vt, meta);
        attn_fwd<<<dim3(BATCH * 32), dim3(512), 0, stream>>>(Q, Kb, Vt, meta, (float*)d_out);
    } else {
        prep_vl<<<1, 64, 0, stream>>>(VL, meta);
        attn_fb<<<dim3(BATCH * (SEQ >> 6)), dim3(256), 0, stream>>>(Q, K, V, meta, (float*)d_out);
    }
}

// Round 7
// 123.056 us; speedup vs baseline: 1.0787x; 1.0787x over previous
//
#include <hip/hip_runtime.h>
#include <hip/hip_bf16.h>

typedef __attribute__((ext_vector_type(8))) short bf16x8;
typedef __attribute__((ext_vector_type(4))) float f32x4;
typedef __attribute__((ext_vector_type(16))) float f32x16;
typedef __attribute__((ext_vector_type(4))) unsigned int u32x4;

#define BATCH 32
#define SEQ   2048
#define PSTR  20    // fallback kernel only
#define KSTR  72    // fallback kernel only
#define VSTR  36    // fallback + prepkv staging
#define LOG2E 1.44269504088896340736f
#define QSCALE (0.125f * LOG2E)
#define NEGL  (-1000000.0f * LOG2E)

__device__ __forceinline__ unsigned int pk2(float lo, float hi) {
    __hip_bfloat162 h2 = __float22bfloat162_rn(make_float2(lo, hi));  // v_cvt_pk_bf16_f32
    return *reinterpret_cast<unsigned int*>(&h2);
}

// v_permlane32_swap_b32: a[32:63] <-> b[0:31].
__device__ __forceinline__ void plswap(unsigned int& a, unsigned int& b) {
    asm volatile("v_permlane32_swap_b32 %0, %1" : "+v"(a), "+v"(b));
}

// standalone prep (fallback path only)
__global__ void prep_vl(const int* __restrict__ VL, int* __restrict__ meta) {
    __shared__ int sv[BATCH];
    const int t = threadIdx.x;
    int odd = (t < 16) ? VL[2 * t + 1] : 0;
    const bool is64 = (__ballot(odd != 0) == 0ULL);
    if (t < BATCH) {
        int x = is64 ? VL[2 * t] : VL[t];
        x = x < 0 ? 0 : (x > SEQ ? SEQ : x);
        sv[t] = x;
    }
    __syncthreads();
    if (t < BATCH) {
        const int x = sv[t];
        int rank = 0;
        for (int j = 0; j < BATCH; ++j) {
            const int y = sv[j];
            rank += (y > x) || (y == x && j < t);
        }
        meta[rank] = x;
        meta[BATCH + rank] = t;
    }
}

// round-7: FRAGMENT-MAJOR workspace. Each MFMA fragment of attn is a
// contiguous lane-ordered 1KB extent:
//   Kw byte off = (b*32+t)*8192 + kh*4096 + kf*1024 + lane*16
//     holding K[b][t*64 + kh*32 + (lane&31)][kf*16 + (lane>>5)*8 .. +7] bf16x8
//   Vw byte off = (b*32+t)*8192 + kh*4096 + q*1024 + lane*16   (q = dt*2+slot)
//     holding packed key-pair uints Vt[d][4c..4c+3], d = (q>>1)*32+(lane&31),
//     c = kh*4 + (q&1)*2 + (lane>>5)
// -> attn loads each fragment with ONE coalesced global_load_dwordx4 (fixes
// round-2's 32-lines-per-instr shatter), enabling a barrier-free main loop.
// Tiles beyond ceil64(vl[b]) are skipped. Block BATCH*32 does the rank-sort.
__global__ __launch_bounds__(256) void prepkv(const float* __restrict__ Kp,
                                              const float* __restrict__ Vp,
                                              const int* __restrict__ VL,
                                              short* __restrict__ Kw,
                                              short* __restrict__ Vw,
                                              int* __restrict__ meta) {
    __shared__ unsigned int l[64 * VSTR];
    __shared__ int sv[BATCH];
    __shared__ int svl;
    const int tid = threadIdx.x;
    if (blockIdx.x == BATCH * 32) {
        if (tid < 64) {
            int odd = (tid < 16) ? VL[2 * tid + 1] : 0;
            const bool is64 = (__ballot(odd != 0) == 0ULL);   // lens>=1
            if (tid < BATCH) {
                int x = is64 ? VL[2 * tid] : VL[tid];
                x = x < 0 ? 0 : (x > SEQ ? SEQ : x);
                sv[tid] = x;
            }
            asm volatile("s_waitcnt lgkmcnt(0)" ::: "memory");
            if (tid < BATCH) {
                const int x = sv[tid];
                int rank = 0;
                for (int j = 0; j < BATCH; ++j) {
                    const int y = sv[j];
                    rank += (y > x) || (y == x && j < tid);
                }
                meta[rank] = x;
                meta[BATCH + rank] = tid;
            }
        }
        return;
    }
    const int b = blockIdx.x >> 5, kt = blockIdx.x & 31, kb = kt * 64;
    // per-block vl: skip tiles attn never reads (kt*64 >= ceil64(vl))
    if (tid < 64) {
        int odd = (tid < 16) ? VL[2 * tid + 1] : 0;
        const bool is64 = (__ballot(odd != 0) == 0ULL);
        if (tid == 0) {
            int x = is64 ? VL[2 * b] : VL[b];
            x = x < 0 ? 0 : (x > SEQ ? SEQ : x);
            svl = x;
        }
    }
    __syncthreads();
    if (kb >= ((svl + 63) & ~63)) return;   // block-uniform exit
    const float* Kv = Kp + ((size_t)b * SEQ + kb) * 64;
    const float* Vb = Vp + ((size_t)b * SEQ + kb) * 64;
    const size_t tbase = (size_t)(b * 32 + kt) * 8192;   // bytes per tile

    // K: 512 chunks of 16B, fragment-major; writes coalesced, reads 32B/lane
    #pragma unroll
    for (int h = 0; h < 2; ++h) {
        const int c = tid + h * 256;
        const int kh = c >> 8, kf = (c >> 6) & 3, ln = c & 63;
        const int key = kh * 32 + (ln & 31), col = kf * 16 + (ln >> 5) * 8;
        f32x4 a = *(const f32x4*)(Kv + key * 64 + col);
        f32x4 d = *(const f32x4*)(Kv + key * 64 + col + 4);
        u32x4 w;
        w.x = pk2(a[0], a[1]); w.y = pk2(a[2], a[3]);
        w.z = pk2(d[0], d[1]); w.w = pk2(d[2], d[3]);
        *(u32x4*)((char*)Kw + tbase + (size_t)c * 16) = w;
    }
    // V: build packed-pair transpose in LDS (unchanged), then fragment-major out
    #pragma unroll
    for (int h = 0; h < 2; ++h) {
        const int u = tid + h * 256;
        const int d4 = (u & 3) + ((u >> 7) << 2);
        const int kp = (u >> 2) & 31;
        f32x4 a = *(const f32x4*)(Vb + (2 * kp) * 64 + d4 * 4);
        f32x4 c = *(const f32x4*)(Vb + (2 * kp + 1) * 64 + d4 * 4);
        #pragma unroll
        for (int j = 0; j < 4; ++j)
            l[(d4 * 4 + j) * VSTR + kp] = pk2(a[j], c[j]);
    }
    __syncthreads();
    #pragma unroll
    for (int h = 0; h < 2; ++h) {
        const int cV = tid + h * 256;
        const int kh = cV >> 8, q = (cV >> 6) & 3, ln = cV & 63;
        const int d = (q >> 1) * 32 + (ln & 31);
        const int cc = kh * 4 + (q & 1) * 2 + (ln >> 5);
        u32x4 w = *(const u32x4*)&l[d * VSTR + 4 * cc];
        *(u32x4*)((char*)Vw + tbase + (size_t)cV * 16) = w;
    }
}

// ---- main: round-7 BARRIER-FREE register loop. r5/r6 post-mortem: three
// schedules all ~45-52us; wall ~3300cyc/wave-tile vs ~300cyc issue -> the
// per-tile __syncthreads protocol (vmcnt(0) drain, 4-8 wave lockstep) is the
// cost. Fragment-major workspace makes every MFMA fragment one coalesced
// global_load_dwordx4 (fixes r2's shatter), so the loop needs NO LDS, NO
// barriers, NO DMA: each wave pipelines load(t+1) under compute(t) with
// compiler-precise per-wave vmcnt. qh-pairs read identical fragments -> L1
// dedupe. Snake-LPT grid unchanged. One end-of-kernel kh-merge (2 barriers). ----
__global__ __launch_bounds__(256, 4)
void attn_fwd(const float* __restrict__ Qp, const short* __restrict__ Kw,
              const short* __restrict__ Vw, const int* __restrict__ meta,
              float* __restrict__ Out) {
    constexpr int S = SEQ;
    __shared__ float mrg[2 * 2048 + 128];   // merge only (16.5 KB)

    const int tid  = threadIdx.x;
    const int wave = tid >> 6, lane = tid & 63;
    const int r31 = lane & 31, hi = lane >> 5;
    const int qh = wave >> 1, kh = wave & 1;   // q-half, key-half

    // snake remap: CU c gets slots {k,15-k,16+k,31-k} -> balanced tile sums
    const int g  = blockIdx.x >> 8;
    const int k8 = (blockIdx.x >> 5) & 7;
    const int qt = blockIdx.x & 31;
    const int slot = (g << 3) + ((g & 1) ? 7 - k8 : k8);

    const int vl = meta[slot], batch = meta[BATCH + slot];
    // per-wave tile count over 64-key tiles (this wave covers keys t*64+kh*32..+31)
    const int ntw = (vl - kh * 32 + 63) >> 6;   // vl>=1 -> never negative-shifted

    // fragment base pointers (include lane offset; tile t at +t*8192B)
    const char* kw = (const char*)Kw + (size_t)batch * 262144 + kh * 4096 + lane * 16;
    const char* vw = (const char*)Vw + (size_t)batch * 262144 + kh * 4096 + lane * 16;

    // Q B-fragments: lane holds Q[qh*32+r31][kf*16+hi*8+j], scale folded
    // (scores exit MFMA in log2 domain)
    bf16x8 qf[4];
    {
        const float* qb = Qp + ((size_t)batch * S + qt * 64 + qh * 32 + r31) * 64 + hi * 8;
        #pragma unroll
        for (int kf = 0; kf < 4; ++kf) {
            f32x4 a = *(const f32x4*)(qb + kf * 16);
            f32x4 c = *(const f32x4*)(qb + kf * 16 + 4);
            union { bf16x8 v; unsigned int u[4]; } qq;
            qq.u[0] = pk2(a[0] * QSCALE, a[1] * QSCALE);
            qq.u[1] = pk2(a[2] * QSCALE, a[3] * QSCALE);
            qq.u[2] = pk2(c[0] * QSCALE, c[1] * QSCALE);
            qq.u[3] = pk2(c[2] * QSCALE, c[3] * QSCALE);
            qf[kf] = qq.v;
        }
    }

    f32x16 o0, o1, zv;
    #pragma unroll
    for (int r = 0; r < 16; ++r) { o0[r] = 0.f; o1[r] = 0.f; zv[r] = 0.f; }
    float lpart = 0.f;

    bf16x8 kk0, kk1, kk2, kk3, vv0, vv1, vv2, vv3;
    if (ntw > 0) {
        kk0 = *(const bf16x8*)(kw);
        kk1 = *(const bf16x8*)(kw + 1024);
        kk2 = *(const bf16x8*)(kw + 2048);
        kk3 = *(const bf16x8*)(kw + 3072);
        vv0 = *(const bf16x8*)(vw);
        vv1 = *(const bf16x8*)(vw + 1024);
        vv2 = *(const bf16x8*)(vw + 2048);
        vv3 = *(const bf16x8*)(vw + 3072);
    }

    for (int t = 0; t < ntw; ++t) {
        // QK: 32 keys (kh half) x 32 q (qh half), log2 domain
        f32x16 st;
        __builtin_amdgcn_s_setprio(1);
        st = __builtin_amdgcn_mfma_f32_32x32x16_bf16(kk0, qf[0], zv, 0, 0, 0);
        st = __builtin_amdgcn_mfma_f32_32x32x16_bf16(kk1, qf[1], st, 0, 0, 0);
        st = __builtin_amdgcn_mfma_f32_32x32x16_bf16(kk2, qf[2], st, 0, 0, 0);
        st = __builtin_amdgcn_mfma_f32_32x32x16_bf16(kk3, qf[3], st, 0, 0, 0);
        __builtin_amdgcn_s_setprio(0);

        // K prefetch t+1 (regs consumed by the MFMAs above; latency hidden
        // under softmax + PV + other waves)
        if (t + 1 < ntw) {
            const char* p = kw + (size_t)(t + 1) * 8192;
            kk0 = *(const bf16x8*)(p);
            kk1 = *(const bf16x8*)(p + 1024);
            kk2 = *(const bf16x8*)(p + 2048);
            kk3 = *(const bf16x8*)(p + 3072);
        }

        // mask the last partial 32-key half (wave-uniform branch)
        const int rem = vl - (t * 64 + kh * 32);
        if (rem < 32) {
            #pragma unroll
            for (int r = 0; r < 16; ++r) {
                const int kl = 4 * hi + (r & 3) + 8 * (r >> 2);
                st[r] = (kl < rem) ? st[r] : NEGL;
            }
        }

        // p = exp2(s') (no max subtraction; masked -> exactly 0)
        #pragma unroll
        for (int r = 0; r < 16; ++r) st[r] = exp2f(st[r]);
        {
            const float a0 = (st[0] + st[1]) + (st[2] + st[3]);
            const float a1 = (st[4] + st[5]) + (st[6] + st[7]);
            const float a2 = (st[8] + st[9]) + (st[10] + st[11]);
            const float a3 = (st[12] + st[13]) + (st[14] + st[15]);
            lpart += (a0 + a1) + (a2 + a3);
        }

        // in-register P^T -> PV B-fragments (T12)
        union { bf16x8 v; unsigned int u[4]; } pf0, pf1;
        {
            unsigned int x0 = pk2(st[0], st[1]),   y0 = pk2(st[4], st[5]);
            unsigned int x1 = pk2(st[2], st[3]),   y1 = pk2(st[6], st[7]);
            plswap(x0, y0); plswap(x1, y1);
            pf0.u[0] = x0; pf0.u[1] = x1; pf0.u[2] = y0; pf0.u[3] = y1;
            unsigned int x2 = pk2(st[8], st[9]),   y2 = pk2(st[12], st[13]);
            unsigned int x3 = pk2(st[10], st[11]), y3 = pk2(st[14], st[15]);
            plswap(x2, y2); plswap(x3, y3);
            pf1.u[0] = x2; pf1.u[1] = x3; pf1.u[2] = y2; pf1.u[3] = y3;
        }

        // O^T += V^T P^T over this wave's 32 keys
        __builtin_amdgcn_s_setprio(1);
        o0 = __builtin_amdgcn_mfma_f32_32x32x16_bf16(vv0, pf0.v, o0, 0, 0, 0);
        o0 = __builtin_amdgcn_mfma_f32_32x32x16_bf16(vv1, pf1.v, o0, 0, 0, 0);
        o1 = __builtin_amdgcn_mfma_f32_32x32x16_bf16(vv2, pf0.v, o1, 0, 0, 0);
        o1 = __builtin_amdgcn_mfma_f32_32x32x16_bf16(vv3, pf1.v, o1, 0, 0, 0);
        __builtin_amdgcn_s_setprio(0);

        // V prefetch t+1
        if (t + 1 < ntw) {
            const char* p = vw + (size_t)(t + 1) * 8192;
            vv0 = *(const bf16x8*)(p);
            vv1 = *(const bf16x8*)(p + 1024);
            vv2 = *(const bf16x8*)(p + 2048);
            vv3 = *(const bf16x8*)(p + 3072);
        }
    }

    // per-(q, key-half) l: lanes l and l+32 hold complementary row sets
    float lw = lpart + __shfl_xor(lpart, 32);

    // cross-wave merge (kh=0 += kh=1): pure sums, once per block
    float* lm = &mrg[4096];
    __syncthreads();
    if (kh == 1) {
        #pragma unroll
        for (int r = 0; r < 16; ++r) mrg[qh * 2048 + r * 64 + lane] = o0[r];
        #pragma unroll
        for (int r = 0; r < 16; ++r) mrg[qh * 2048 + (16 + r) * 64 + lane] = o1[r];
        lm[qh * 64 + lane] = lw;
    }
    __syncthreads();
    if (kh == 0) {
        #pragma unroll
        for (int r = 0; r < 16; ++r) o0[r] += mrg[qh * 2048 + r * 64 + lane];
        #pragma unroll
        for (int r = 0; r < 16; ++r) o1[r] += mrg[qh * 2048 + (16 + r) * 64 + lane];
        lw += lm[qh * 64 + lane];
        const float inv = (lw > 0.f) ? 1.0f / lw : 0.f;
        const size_t orow = ((size_t)batch * S + qt * 64 + qh * 32 + r31) * 64;
        #pragma unroll
        for (int g4 = 0; g4 < 4; ++g4) {
            f32x4 w;
            #pragma unroll
            for (int j = 0; j < 4; ++j) w[j] = o0[g4 * 4 + j] * inv;
            *(f32x4*)(Out + orow + g4 * 8 + hi * 4) = w;
        }
        #pragma unroll
        for (int g4 = 0; g4 < 4; ++g4) {
            f32x4 w;
            #pragma unroll
            for (int j = 0; j < 4; ++j) w[j] = o1[g4 * 4 + j] * inv;
            *(f32x4*)(Out + orow + 32 + g4 * 8 + hi * 4) = w;
        }
    }
}

// ---------------- fallback (used only if ws too small) ----------------
__device__ __forceinline__ void load_tile_fb(const float* __restrict__ Kb,
                                             const float* __restrict__ Vb,
                                             int tid, f32x4 kv[4], f32x4 vv[4]) {
    #pragma unroll
    for (int h = 0; h < 4; ++h) {
        const int c = tid + h * 256;
        kv[h] = *(const f32x4*)(Kb + (c >> 4) * 64 + (c & 15) * 4);
    }
    #pragma unroll
    for (int h = 0; h < 2; ++h) {
        const int u  = tid + h * 256;
        const int d4 = (u & 3) + ((u >> 7) << 2);
        const int kp = (u >> 2) & 31;
        vv[2 * h]     = *(const f32x4*)(Vb + (2 * kp) * 64 + d4 * 4);
        vv[2 * h + 1] = *(const f32x4*)(Vb + (2 * kp + 1) * 64 + d4 * 4);
    }
}

__global__ __launch_bounds__(256, 4)
void attn_fb(const float* __restrict__ Qp, const float* __restrict__ Kp,
             const float* __restrict__ Vp, const int* __restrict__ meta,
             float* __restrict__ Out) {
    constexpr int S = SEQ;
    constexpr int qtiles = S >> 6;
    __shared__ short        lK [64 * KSTR];
    __shared__ unsigned int lVt[64 * VSTR];
    __shared__ unsigned int lPt[4 * 32 * PSTR];
    const int tid = threadIdx.x;
    const int wave = tid >> 6, lane = tid & 63;
    const int l15 = lane & 15, grp = lane >> 4;
    const int slot = blockIdx.x / qtiles, qt = blockIdx.x % qtiles;
    const int vl = meta[slot], batch = meta[BATCH + slot];
    const int ntiles = (vl + 63) >> 6;
    const float* Kb = Kp + (size_t)batch * S * 64;
    const float* Vb = Vp + (size_t)batch * S * 64;
    bf16x8 qf[2];
    {
        const float* qb = Qp + ((size_t)batch * S + qt * 64 + wave * 16 + l15) * 64 + grp * 8;
        #pragma unroll
        for (int kf = 0; kf < 2; ++kf) {
            f32x4 a = *(const f32x4*)(qb + kf * 32);
            f32x4 b = *(const f32x4*)(qb + kf * 32 + 4);
            union { bf16x8 v; unsigned int u[4]; } qq;
            qq.u[0] = pk2(a[0], a[1]); qq.u[1] = pk2(a[2], a[3]);
            qq.u[2] = pk2(b[0], b[1]); qq.u[3] = pk2(b[2], b[3]);
            qf[kf] = qq.v;
        }
    }
    f32x4 o[4] = {{0.f,0.f,0.f,0.f},{0.f,0.f,0.f,0.f},{0.f,0.f,0.f,0.f},{0.f,0.f,0.f,0.f}};
    float mrun = -INFINITY, lrun = 0.f;
    unsigned int* pw = &lPt[wave * 32 * PSTR];
    f32x4 kv[4], vv[4];
    if (ntiles > 0) load_tile_fb(Kb, Vb, tid, kv, vv);
    for (int kt = 0; kt < ntiles; ++kt) {
        const int kb = kt * 64;
        __syncthreads();
        #pragma unroll
        for (int h = 0; h < 4; ++h) {
            const int c = tid + h * 256;
            const int row = c >> 4, col = (c & 15) * 4;
            union { f32x4 f; float e[4]; } x; x.f = kv[h];
            unsigned int* dst = (unsigned int*)&lK[row * KSTR + col];
            dst[0] = pk2(x.e[0], x.e[1]); dst[1] = pk2(x.e[2], x.e[3]);
        }
        #pragma unroll
        for (int h = 0; h < 2; ++h) {
            const int u  = tid + h * 256;
            const int d4 = (u & 3) + ((u >> 7) << 2);
            const int kp = (u >> 2) & 31;
            union { f32x4 f; float e[4]; } a, b;
            a.f = vv[2 * h]; b.f = vv[2 * h + 1];
            #pragma unroll
            for (int j = 0; j < 4; ++j)
                lVt[(d4 * 4 + j) * VSTR + kp] = pk2(a.e[j], b.e[j]);
        }
        if (kt + 1 < ntiles) load_tile_fb(Kb + (size_t)(kb + 64) * 64, Vb + (size_t)(kb + 64) * 64, tid, kv, vv);
        __syncthreads();
        f32x4 st[4] = {{0.f,0.f,0.f,0.f},{0.f,0.f,0.f,0.f},{0.f,0.f,0.f,0.f},{0.f,0.f,0.f,0.f}};
        #pragma unroll
        for (int kf = 0; kf < 2; ++kf) {
            #pragma unroll
            for (int ct = 0; ct < 4; ++ct) {
                bf16x8 kfr = *(const bf16x8*)&lK[(ct * 16 + l15) * KSTR + kf * 32 + grp * 8];
                st[ct] = __builtin_amdgcn_mfma_f32_16x16x32_bf16(kfr, qf[kf], st[ct], 0, 0, 0);
            }
        }
        #pragma unroll
        for (int ct = 0; ct < 4; ++ct)
            #pragma unroll
            for (int r = 0; r < 4; ++r) {
                const bool valid = (kb + ct * 16 + grp * 4 + r) < vl;
                st[ct][r] = valid ? st[ct][r] * (0.125f * LOG2E) : NEGL;
            }
        float t0 = fmaxf(fmaxf(st[0][0], st[0][1]), fmaxf(st[0][2], st[0][3]));
        float t1 = fmaxf(fmaxf(st[1][0], st[1][1]), fmaxf(st[1][2], st[1][3]));
        float t2 = fmaxf(fmaxf(st[2][0], st[2][1]), fmaxf(st[2][2], st[2][3]));
        float t3 = fmaxf(fmaxf(st[3][0], st[3][1]), fmaxf(st[3][2], st[3][3]));
        float tm = fmaxf(fmaxf(t0, t1), fmaxf(t2, t3));
        tm = fmaxf(tm, __shfl_xor(tm, 16));
        tm = fmaxf(tm, __shfl_xor(tm, 32));
        const float mnew  = fmaxf(mrun, tm);
        const float alpha = exp2f(mrun - mnew);
        mrun = mnew;
        lrun *= alpha;
        #pragma unroll
        for (int dt = 0; dt < 4; ++dt)
            #pragma unroll
            for (int r = 0; r < 4; ++r) o[dt][r] *= alpha;
        float rs = 0.f;
        #pragma unroll
        for (int ct = 0; ct < 4; ++ct) {
            #pragma unroll
            for (int r = 0; r < 4; ++r) {
                st[ct][r] = exp2f(st[ct][r] - mrun);
                rs += st[ct][r];
            }
            #pragma unroll
            for (int a = 0; a < 2; ++a)
                pw[(ct * 8 + grp * 2 + a) * PSTR + l15] = pk2(st[ct][2 * a], st[ct][2 * a + 1]);
        }
        rs += __shfl_xor(rs, 16);
        rs += __shfl_xor(rs, 32);
        lrun += rs;
        asm volatile("s_waitcnt lgkmcnt(0)" ::: "memory");
        #pragma unroll
        for (int kk = 0; kk < 2; ++kk) {
            union { bf16x8 v; unsigned int u[4]; } pf;
            #pragma unroll
            for (int jj = 0; jj < 4; ++jj)
                pf.u[jj] = pw[(kk * 16 + grp * 4 + jj) * PSTR + l15];
            #pragma unroll
            for (int dt = 0; dt < 4; ++dt) {
                bf16x8 vf = *(const bf16x8*)&lVt[(dt * 16 + l15) * VSTR + kk * 16 + grp * 4];
                o[dt] = __builtin_amdgcn_mfma_f32_16x16x32_bf16(vf, pf.v, o[dt], 0, 0, 0);
            }
        }
    }
    const float inv = (lrun > 0.f) ? 1.0f / lrun : 0.f;
    const size_t orow = ((size_t)batch * S + qt * 64 + wave * 16 + l15) * 64;
    #pragma unroll
    for (int dt = 0; dt < 4; ++dt) {
        f32x4 w = o[dt];
        w[0] *= inv; w[1] *= inv; w[2] *= inv; w[3] *= inv;
        *(f32x4*)(Out + orow + dt * 16 + grp * 4) = w;
    }
}

extern "C" void kernel_launch(void* const* d_in, const int* in_sizes, int n_in,
                              void* d_out, int out_size, void* d_ws, size_t ws_size,
                              hipStream_t stream) {
    const float* Q  = (const float*)d_in[0];
    const float* K  = (const float*)d_in[1];
    const float* V  = (const float*)d_in[2];
    const int*   VL = (const int*)d_in[3];
    int* meta = (int*)d_ws;                    // 64 ints
    const size_t need = 512 + 2 * (size_t)BATCH * SEQ * 64 * sizeof(short);  // ~16.8 MB
    if (ws_size >= need) {
        short* Kw = (short*)((char*)d_ws + 512);
        short* Vw = Kw + (size_t)BATCH * SEQ * 64;
        prepkv<<<dim3(BATCH * 32 + 1), dim3(256), 0, stream>>>(K, V, VL, Kw, Vw, meta);
        attn_fwd<<<dim3(BATCH * 32), dim3(256), 0, stream>>>(Q, Kw, Vw, meta, (float*)d_out);
    } else {
        prep_vl<<<1, 64, 0, stream>>>(VL, meta);
        attn_fb<<<dim3(BATCH * (SEQ >> 6)), dim3(256), 0, stream>>>(Q, K, V, meta, (float*)d_out);
    }
}